// Round 16
// baseline (83.646 us; speedup 1.0000x reference)
//
#include <hip/hip_runtime.h>
#include <hip/hip_bf16.h>
#include <math.h>

typedef _Float16 f16x8 __attribute__((ext_vector_type(8)));
typedef _Float16 f16x4 __attribute__((ext_vector_type(4)));
typedef _Float16 f16x2 __attribute__((ext_vector_type(2)));
typedef __fp16 fp16x2 __attribute__((ext_vector_type(2)));
typedef float f32x4 __attribute__((ext_vector_type(4)));

#define MFMA16(a, b, c) __builtin_amdgcn_mfma_f32_16x16x32_f16((a), (b), (c), 0, 0, 0)

typedef __attribute__((address_space(3))) char as3_char;
typedef __attribute__((address_space(1))) const char as1_char;
__device__ __forceinline__ void glds16(const void* g, void* l) {
  __builtin_amdgcn_global_load_lds((as1_char*)g, (as3_char*)l, 16, 0, 0);
}

union F16x8u { f16x8 v; f16x2 h[4]; };

__device__ __forceinline__ f16x2 pkrtz(float a, float b) {
  fp16x2 r = __builtin_amdgcn_cvt_pkrtz(a, b);
  return __builtin_bit_cast(f16x2, r);
}

// ---------------- kernel 0: W -> chunked, pre-swizzled f16 hi/lo staging ----
// Wstg: 12 chunks x 1536 segs x 16B. Seg s2 = p*768 + r*4 + gg holds
// WT_p[r][c0*32 + g*8 .. +8] where g = gg ^ ((r>>1)&3)  (bank-spread swizzle).
__global__ __launch_bounds__(256) void wprep_kernel(
    const float* __restrict__ Wq, const float* __restrict__ Wk, const float* __restrict__ Wv,
    _Float16* __restrict__ wstg) {
  int s = blockIdx.x * 256 + threadIdx.x;  // 0..18431
  int c0 = s / 1536, s2 = s % 1536;
  int p = s2 / 768, r = (s2 % 768) / 4, gg = s2 & 3;
  int g = gg ^ ((r >> 1) & 3);
  int sel = r >> 6, h = r & 63;
  const float* W = (sel == 0) ? Wq : (sel == 1) ? Wk : Wv;
  f16x8 o;
#pragma unroll
  for (int e = 0; e < 8; ++e) {
    float val = W[(c0 * 32 + g * 8 + e) * 64 + h];
    _Float16 hi = (_Float16)val;
    o[e] = p ? (_Float16)(val - (float)hi) : hi;
  }
  *(f16x8*)&wstg[(size_t)s * 8] = o;
}

// ---------------- fused kernel: one block per batch, 8 waves ---------------
// Wave w owns q-rows {16w..16w+15} U {240-16w..255-16w}. 512 thr -> 256-reg
// budget (no spill; ~236 used incl depth-1 frag pipeline).
// Phase A: W LDS-dbuf via glds (counted vmcnt), x in regs 2-deep; B-frags
// ct-software-pipelined (issue ct+1's 5 ds_read_b128 before ct's MFMAs).
// Phase B: causal flash attention, merged-set shared kh/kl/vT reads.
__global__ __launch_bounds__(512, 2) void fused_kernel(
    const float* __restrict__ x,
    const _Float16* __restrict__ wstg,
    float* __restrict__ out) {
  __shared__ __align__(16) char smem[156672];
  _Float16* kh = (_Float16*)smem;              // [256][72] f16 (36864 B)
  _Float16* kl = (_Float16*)(smem + 36864);    // [256][72] f16
  _Float16* vT = (_Float16*)(smem + 73728);    // [64][264] f16 (33792 B)
  char* wbuf0 = smem + 107520;                 // W chunk buf (24576 B)
  char* wbuf1 = smem + 132096;                 // W chunk buf (24576 B)
  _Float16* slc = (_Float16*)(smem + 107520);  // ALIAS: 8 x [32][72] (epilogue/B)

  const int tid = threadIdx.x;
  const int wave = tid >> 6, lane = tid & 63;
  const int g = lane >> 4, l16 = lane & 15;
  const int b = blockIdx.x;
  const int rset[2] = {16 * wave, 240 - 16 * wave};
  const float* xb = x + (size_t)b * 98304;  // 256*384
  _Float16* wsl = slc + wave * 2304;        // this wave's private [32][72] slice

  const float K2 = 28.270933f;  // sqrt(384) * log2(e)
  const float NINF = -__builtin_inff();

  const float* xrow0 = xb + (size_t)(rset[0] + l16) * 384 + g * 8;
  const float* xrow1 = xb + (size_t)(rset[1] + l16) * 384 + g * 8;

  // ---------------- Phase A ----------------
  f32x4 qa[2][4] = {}, ka[2][4] = {}, va[2][4] = {};
  float4 buf[3][2][2];  // [stage][set][half], statically indexed (full unroll)

  // prologue: W(0) glds, then x(0), x(1)
#pragma unroll
  for (int i = 0; i < 3; ++i) {
    int seg0 = wave * 192 + i * 64;
    glds16(wstg + (size_t)(seg0 + lane) * 8, wbuf0 + seg0 * 16);
  }
  __builtin_amdgcn_sched_barrier(0);
#pragma unroll
  for (int p = 0; p < 2; ++p) {
    buf[p][0][0] = *(const float4*)(xrow0 + p * 32);
    buf[p][0][1] = *(const float4*)(xrow0 + p * 32 + 4);
    buf[p][1][0] = *(const float4*)(xrow1 + p * 32);
    buf[p][1][1] = *(const float4*)(xrow1 + p * 32 + 4);
  }
  __builtin_amdgcn_sched_barrier(0);
  asm volatile("s_waitcnt vmcnt(4) lgkmcnt(0)" ::: "memory");
  __builtin_amdgcn_s_barrier();
  __builtin_amdgcn_sched_barrier(0);

#pragma unroll
  for (int c = 0; c < 12; ++c) {
    // issue glds for W(c+1) into the other buffer
    if (c < 11) {
      char* nb = ((c + 1) & 1) ? wbuf1 : wbuf0;
      const _Float16* src = wstg + (size_t)(c + 1) * 12288;  // 1536*8 f16
#pragma unroll
      for (int i = 0; i < 3; ++i) {
        int seg0 = wave * 192 + i * 64;
        glds16(src + (size_t)(seg0 + lane) * 8, nb + seg0 * 16);
      }
    }
    __builtin_amdgcn_sched_barrier(0);
    // issue x prefetch for chunk c+2
    if (c < 10) {
      buf[(c + 2) % 3][0][0] = *(const float4*)(xrow0 + (c + 2) * 32);
      buf[(c + 2) % 3][0][1] = *(const float4*)(xrow0 + (c + 2) * 32 + 4);
      buf[(c + 2) % 3][1][0] = *(const float4*)(xrow1 + (c + 2) * 32);
      buf[(c + 2) % 3][1][1] = *(const float4*)(xrow1 + (c + 2) * 32 + 4);
    }
    __builtin_amdgcn_sched_barrier(0);

    // convert chunk c to f16 hi/lo A-fragments (packed cvt)
    const char* wb = (c & 1) ? wbuf1 : wbuf0;
    f16x8 ah[2], al[2];
#pragma unroll
    for (int s = 0; s < 2; ++s) {
      float vv[8] = {buf[c % 3][s][0].x, buf[c % 3][s][0].y, buf[c % 3][s][0].z,
                     buf[c % 3][s][0].w, buf[c % 3][s][1].x, buf[c % 3][s][1].y,
                     buf[c % 3][s][1].z, buf[c % 3][s][1].w};
      F16x8u uh, ul;
#pragma unroll
      for (int k2 = 0; k2 < 4; ++k2) {
        float a = vv[2 * k2], bb = vv[2 * k2 + 1];
        f16x2 hp = pkrtz(a, bb);
        uh.h[k2] = hp;
        ul.h[k2] = pkrtz(a - (float)hp[0], bb - (float)hp[1]);
      }
      ah[s] = uh.v;
      al[s] = ul.v;
    }

    // compute: ct-pipelined B-frags (depth 1, two parities). Issue ct+1's
    // 5 ds_read_b128 BEFORE ct's MFMA cluster; sched_barrier pins the issue,
    // compiler inserts the counted lgkmcnt. 56 MFMA per wave per chunk.
    f16x8 bqh[2], bql[2], bkh[2], bkl[2], bvh[2];
    {
      const int rq = l16, rk = 64 + l16, rv = 128 + l16;  // ct = 0
      bqh[0] = *(const f16x8*)(wb + (0 * 768 + rq * 4 + (g ^ ((rq >> 1) & 3))) * 16);
      bql[0] = *(const f16x8*)(wb + (1 * 768 + rq * 4 + (g ^ ((rq >> 1) & 3))) * 16);
      bkh[0] = *(const f16x8*)(wb + (0 * 768 + rk * 4 + (g ^ ((rk >> 1) & 3))) * 16);
      bkl[0] = *(const f16x8*)(wb + (1 * 768 + rk * 4 + (g ^ ((rk >> 1) & 3))) * 16);
      bvh[0] = *(const f16x8*)(wb + (0 * 768 + rv * 4 + (g ^ ((rv >> 1) & 3))) * 16);
    }
#pragma unroll
    for (int ct = 0; ct < 4; ++ct) {
      const int pc = ct & 1, pn = pc ^ 1;
      if (ct < 3) {
        const int rq = (ct + 1) * 16 + l16;
        const int rk = 64 + rq, rv = 128 + rq;
        bqh[pn] = *(const f16x8*)(wb + (0 * 768 + rq * 4 + (g ^ ((rq >> 1) & 3))) * 16);
        bql[pn] = *(const f16x8*)(wb + (1 * 768 + rq * 4 + (g ^ ((rq >> 1) & 3))) * 16);
        bkh[pn] = *(const f16x8*)(wb + (0 * 768 + rk * 4 + (g ^ ((rk >> 1) & 3))) * 16);
        bkl[pn] = *(const f16x8*)(wb + (1 * 768 + rk * 4 + (g ^ ((rk >> 1) & 3))) * 16);
        bvh[pn] = *(const f16x8*)(wb + (0 * 768 + rv * 4 + (g ^ ((rv >> 1) & 3))) * 16);
      }
      __builtin_amdgcn_sched_barrier(0);  // pin prefetch issue above MFMAs
      __builtin_amdgcn_s_setprio(1);
#pragma unroll
      for (int s = 0; s < 2; ++s) {
        qa[s][ct] = MFMA16(ah[s], bqh[pc], qa[s][ct]);
        qa[s][ct] = MFMA16(al[s], bqh[pc], qa[s][ct]);
        qa[s][ct] = MFMA16(ah[s], bql[pc], qa[s][ct]);
        ka[s][ct] = MFMA16(ah[s], bkh[pc], ka[s][ct]);
        ka[s][ct] = MFMA16(al[s], bkh[pc], ka[s][ct]);
        ka[s][ct] = MFMA16(ah[s], bkl[pc], ka[s][ct]);
        va[s][ct] = MFMA16(ah[s], bvh[pc], va[s][ct]);  // v: single pass
      }
      __builtin_amdgcn_s_setprio(0);
      __builtin_amdgcn_sched_barrier(0);
    }
    // counted drain: W(c+1)+x(c+1) done, x(c+2) stays in flight
    if (c < 10) {
      asm volatile("s_waitcnt vmcnt(4) lgkmcnt(0)" ::: "memory");
    } else if (c == 10) {
      asm volatile("s_waitcnt vmcnt(0) lgkmcnt(0)" ::: "memory");
    } else {
      asm volatile("s_waitcnt lgkmcnt(0)" ::: "memory");
    }
    __builtin_amdgcn_s_barrier();
    __builtin_amdgcn_sched_barrier(0);
  }

  // ---- epilogue: k hi/lo + vT to LDS; q redistributed via per-wave slice ----
#pragma unroll
  for (int s = 0; s < 2; ++s) {
    const int rs = rset[s];
#pragma unroll
    for (int ct = 0; ct < 4; ++ct) {
      const int h = ct * 16 + l16;
#pragma unroll
      for (int j = 0; j < 4; ++j) {
        const int row = rs + 4 * g + j;
        float kv = ka[s][ct][j];
        _Float16 khv = (_Float16)kv;
        kh[row * 72 + h] = khv;
        kl[row * 72 + h] = (_Float16)(kv - (float)khv);
        vT[h * 264 + row] = (_Float16)va[s][ct][j];
      }
    }
  }
  f16x8 qhf[2][2], qlf[2][2];  // [set][ks] B-fragments of q
#pragma unroll
  for (int ct = 0; ct < 4; ++ct) {
    const int h = ct * 16 + l16;
#pragma unroll
    for (int j = 0; j < 4; ++j) {
      const int rl = 4 * g + j;
      float qv = qa[0][ct][j];
      _Float16 qh = (_Float16)qv;
      wsl[(rl * 2 + 0) * 72 + h] = qh;
      wsl[(rl * 2 + 1) * 72 + h] = (_Float16)(qv - (float)qh);
    }
  }
  __syncthreads();  // (1) k/v + set0 slice flushed
#pragma unroll
  for (int ks = 0; ks < 2; ++ks) {
    qhf[0][ks] = *(const f16x8*)&wsl[(l16 * 2 + 0) * 72 + ks * 32 + g * 8];
    qlf[0][ks] = *(const f16x8*)&wsl[(l16 * 2 + 1) * 72 + ks * 32 + g * 8];
  }
  __syncthreads();  // (2) set0 reads done before overwrite
#pragma unroll
  for (int ct = 0; ct < 4; ++ct) {
    const int h = ct * 16 + l16;
#pragma unroll
    for (int j = 0; j < 4; ++j) {
      const int rl = 4 * g + j;
      float qv = qa[1][ct][j];
      _Float16 qh = (_Float16)qv;
      wsl[(rl * 2 + 0) * 72 + h] = qh;
      wsl[(rl * 2 + 1) * 72 + h] = (_Float16)(qv - (float)qh);
    }
  }
  __syncthreads();  // (3) set1 slice flushed
#pragma unroll
  for (int ks = 0; ks < 2; ++ks) {
    qhf[1][ks] = *(const f16x8*)&wsl[(l16 * 2 + 0) * 72 + ks * 32 + g * 8];
    qlf[1][ks] = *(const f16x8*)&wsl[(l16 * 2 + 1) * 72 + ks * 32 + g * 8];
  }
  asm volatile("s_waitcnt lgkmcnt(0)" ::: "memory");
  __builtin_amdgcn_sched_barrier(0);

  // ---------------- Phase B: causal flash attention (no barriers) ----------
  // Merged sets: kh/kl and vT fragments are set-independent -> read once.
  _Float16* psl = wsl;  // per-wave private P slice [32][72]
  float mrun[2] = {NINF, NINF}, srun[2] = {0.f, 0.f};
  f32x4 O[2][4] = {};
  const int rs0 = rset[0], rs1 = rset[1];
  const int qr0 = rs0 + l16, qr1 = rs1 + l16;

  for (int c = 0; c < 4; ++c) {
    const int kb = c * 64;
    const bool a0 = (kb <= rs0 + 15);  // wave-uniform
    const bool a1 = (kb <= rs1 + 15);  // wave-uniform
    if (!a0 && !a1) continue;
    f32x4 s0[4] = {}, s1[4] = {};
#pragma unroll
    for (int kt = 0; kt < 4; ++kt) {
      const int kr = kb + 16 * kt;
      const bool t0 = a0 && (kr <= rs0 + 15);
      const bool t1 = a1 && (kr <= rs1 + 15);
      if (!t0 && !t1) continue;
#pragma unroll
      for (int ks = 0; ks < 2; ++ks) {
        const int ko = (kr + l16) * 72 + ks * 32 + g * 8;
        f16x8 akh = *(const f16x8*)&kh[ko];
        f16x8 akl = *(const f16x8*)&kl[ko];
        __builtin_amdgcn_s_setprio(1);
        if (t0) {
          s0[kt] = MFMA16(akh, qhf[0][ks], s0[kt]);
          s0[kt] = MFMA16(akl, qhf[0][ks], s0[kt]);
          s0[kt] = MFMA16(akh, qlf[0][ks], s0[kt]);
        }
        if (t1) {
          s1[kt] = MFMA16(akh, qhf[1][ks], s1[kt]);
          s1[kt] = MFMA16(akl, qhf[1][ks], s1[kt]);
          s1[kt] = MFMA16(akh, qlf[1][ks], s1[kt]);
        }
        __builtin_amdgcn_s_setprio(0);
      }
    }
    // ---- softmax per set (packed P writes) ----
    if (a0) {
      float cm = NINF;
#pragma unroll
      for (int kt = 0; kt < 4; ++kt)
#pragma unroll
        for (int j = 0; j < 4; ++j) {
          const int krow = kb + 16 * kt + 4 * g + j;
          float sv = (krow <= qr0) ? s0[kt][j] : NINF;
          s0[kt][j] = sv;
          cm = fmaxf(cm, sv);
        }
      cm = fmaxf(cm, __shfl_xor(cm, 16));
      cm = fmaxf(cm, __shfl_xor(cm, 32));
      const float mn = fmaxf(mrun[0], cm);
      const float scl = exp2f(K2 * (mrun[0] - mn));
      mrun[0] = mn;
      float cs = 0.f;
#pragma unroll
      for (int kt = 0; kt < 4; ++kt) {
        float p0 = exp2f(K2 * (s0[kt][0] - mn));
        float p1 = exp2f(K2 * (s0[kt][1] - mn));
        float p2 = exp2f(K2 * (s0[kt][2] - mn));
        float p3 = exp2f(K2 * (s0[kt][3] - mn));
        cs += (p0 + p1) + (p2 + p3);
        f16x2 lo2 = pkrtz(p0, p1), hi2 = pkrtz(p2, p3);
        f16x4 pk = {lo2[0], lo2[1], hi2[0], hi2[1]};
        *(f16x4*)&psl[l16 * 72 + kt * 16 + 4 * g] = pk;
      }
      cs += __shfl_xor(cs, 16);
      cs += __shfl_xor(cs, 32);
      srun[0] = srun[0] * scl + cs;
#pragma unroll
      for (int ht = 0; ht < 4; ++ht) O[0][ht] *= scl;
    }
    if (a1) {
      float cm = NINF;
#pragma unroll
      for (int kt = 0; kt < 4; ++kt)
#pragma unroll
        for (int j = 0; j < 4; ++j) {
          const int krow = kb + 16 * kt + 4 * g + j;
          float sv = (krow <= qr1) ? s1[kt][j] : NINF;
          s1[kt][j] = sv;
          cm = fmaxf(cm, sv);
        }
      cm = fmaxf(cm, __shfl_xor(cm, 16));
      cm = fmaxf(cm, __shfl_xor(cm, 32));
      const float mn = fmaxf(mrun[1], cm);
      const float scl = exp2f(K2 * (mrun[1] - mn));
      mrun[1] = mn;
      float cs = 0.f;
#pragma unroll
      for (int kt = 0; kt < 4; ++kt) {
        float p0 = exp2f(K2 * (s1[kt][0] - mn));
        float p1 = exp2f(K2 * (s1[kt][1] - mn));
        float p2 = exp2f(K2 * (s1[kt][2] - mn));
        float p3 = exp2f(K2 * (s1[kt][3] - mn));
        cs += (p0 + p1) + (p2 + p3);
        f16x2 lo2 = pkrtz(p0, p1), hi2 = pkrtz(p2, p3);
        f16x4 pk = {lo2[0], lo2[1], hi2[0], hi2[1]};
        *(f16x4*)&psl[(16 + l16) * 72 + kt * 16 + 4 * g] = pk;
      }
      cs += __shfl_xor(cs, 16);
      cs += __shfl_xor(cs, 32);
      srun[1] = srun[1] * scl + cs;
#pragma unroll
      for (int ht = 0; ht < 4; ++ht) O[1][ht] *= scl;
    }
    // make P writes visible to this wave's reads, defeat MFMA hoisting
    asm volatile("s_waitcnt lgkmcnt(0)" ::: "memory");
    __builtin_amdgcn_sched_barrier(0);
    // ---- PV with shared vT reads ----
#pragma unroll
    for (int ks2 = 0; ks2 < 2; ++ks2) {
      f16x8 bp0 = {}, bp1 = {};
      if (a0) bp0 = *(const f16x8*)&psl[l16 * 72 + ks2 * 32 + g * 8];
      if (a1) bp1 = *(const f16x8*)&psl[(16 + l16) * 72 + ks2 * 32 + g * 8];
#pragma unroll
      for (int ht = 0; ht < 4; ++ht) {
        f16x8 av = *(const f16x8*)&vT[(ht * 16 + l16) * 264 + kb + ks2 * 32 + g * 8];
        __builtin_amdgcn_s_setprio(1);
        if (a0) O[0][ht] = MFMA16(av, bp0, O[0][ht]);
        if (a1) O[1][ht] = MFMA16(av, bp1, O[1][ht]);
        __builtin_amdgcn_s_setprio(0);
      }
    }
  }

  // ---- output: out[qr][h] = O^T[h][qr] / srun ----
#pragma unroll
  for (int s = 0; s < 2; ++s) {
    const int qr = rset[s] + l16;
    const float inv = 1.0f / srun[s];
#pragma unroll
    for (int ht = 0; ht < 4; ++ht) {
      f32x4 r = O[s][ht] * inv;
      *(f32x4*)&out[((size_t)b * 256 + qr) * 64 + ht * 16 + 4 * g] = r;
    }
  }
}

// ---------------------------------------------------------------------------
extern "C" void kernel_launch(void* const* d_in, const int* in_sizes, int n_in,
                              void* d_out, int out_size, void* d_ws, size_t ws_size,
                              hipStream_t stream) {
  const float* x  = (const float*)d_in[0];
  const float* Wq = (const float*)d_in[1];
  const float* Wk = (const float*)d_in[2];
  const float* Wv = (const float*)d_in[3];

  _Float16* wstg = (_Float16*)d_ws;  // 12*1536*16B = 294912 B

  wprep_kernel<<<72, 256, 0, stream>>>(Wq, Wk, Wv, wstg);
  fused_kernel<<<512, 512, 0, stream>>>(x, wstg, (float*)d_out);
}